// Round 1
// baseline (276.925 us; speedup 1.0000x reference)
//
#include <hip/hip_runtime.h>
#include <stdint.h>

// Problem constants
#define DM    1024
#define LP    16
#define NH    8
#define BP_N  2048          // B * S / PATCH_LEN = 8*4096/16
#define OUT_LATENT (2048*1024)
#define SCALE 0.08838834764831845f  // 1/sqrt(128)

typedef float f32x4v __attribute__((ext_vector_type(4)));
typedef short s16x8  __attribute__((ext_vector_type(8)));

static __device__ inline unsigned short f2bf(float f) {
    union { float f; uint32_t u; } v; v.f = f;
    uint32_t u = v.u;
    return (unsigned short)((u + 0x7FFFu + ((u >> 16) & 1u)) >> 16); // RNE
}
static __device__ inline float bflo(uint32_t u) {
    union { uint32_t u; float f; } v; v.u = u << 16; return v.f;
}
static __device__ inline float bfhi(uint32_t u) {
    union { uint32_t u; float f; } v; v.u = u & 0xFFFF0000u; return v.f;
}

// ---------------------------------------------------------------------------
// Kernel 1: convert wv (rows 2048..3071 of in_proj_w) and out_w to bf16
// grid 2048 x 256: blocks [0,1024) -> wv, [1024,2048) -> out_w; 1024 elems/blk
__global__ __launch_bounds__(256) void k_convw(
    const float* __restrict__ wv_src, const float* __restrict__ ow_src,
    unsigned short* __restrict__ wv_dst, unsigned short* __restrict__ ow_dst) {
    int t = threadIdx.x, b = blockIdx.x;
    const float* src; unsigned short* dst; int idx;
    if (b < 1024) { src = wv_src; dst = wv_dst; idx = b * 1024 + t * 4; }
    else          { src = ow_src; dst = ow_dst; idx = (b - 1024) * 1024 + t * 4; }
    float4 f = *(const float4*)(src + idx);
    ushort4 o; o.x = f2bf(f.x); o.y = f2bf(f.y); o.z = f2bf(f.z); o.w = f2bf(f.w);
    *(ushort4*)(dst + idx) = o;
}

// ---------------------------------------------------------------------------
// Kernel 2: q[d] = patch_query . wq[d,:] + bq[d].  grid 256 x 256 (1 wave/d)
__global__ __launch_bounds__(256) void k_qvec(
    const float* __restrict__ pq, const float* __restrict__ ipw,
    const float* __restrict__ ipb, float* __restrict__ qv) {
    int t = threadIdx.x, wave = t >> 6, lane = t & 63;
    int d = blockIdx.x * 4 + wave;
    const float* wrow = ipw + (size_t)d * 1024;
    float acc = 0.f;
    #pragma unroll
    for (int i = 0; i < 16; ++i) { int j = lane + i * 64; acc = fmaf(pq[j], wrow[j], acc); }
    #pragma unroll
    for (int m = 32; m >= 1; m >>= 1) acc += __shfl_xor(acc, m);
    if (lane == 0) qv[d] = acc + ipb[d];
}

// ---------------------------------------------------------------------------
// Kernel 3: qk[h][j] = SCALE * sum_d q[h*128+d] * wk[h*128+d][j]  (bf16 out)
//           sb[h]    = SCALE * sum_d q[h*128+d] * bk[h*128+d]
// grid 8 x 256
__global__ __launch_bounds__(256) void k_qk(
    const float* __restrict__ qv, const float* __restrict__ ipw,
    const float* __restrict__ ipb, unsigned short* __restrict__ qkb,
    float* __restrict__ sb) {
    __shared__ float qs[128];
    int h = blockIdx.x, t = threadIdx.x;
    if (t < 128) qs[t] = qv[h * 128 + t];
    __syncthreads();
    float a0 = 0.f, a1 = 0.f, a2 = 0.f, a3 = 0.f;
    const float* wbase = ipw + (size_t)(1024 + h * 128) * 1024;
    for (int d = 0; d < 128; ++d) {
        float qd = qs[d];
        const float* wr = wbase + (size_t)d * 1024;
        a0 = fmaf(qd, wr[t], a0);
        a1 = fmaf(qd, wr[t + 256], a1);
        a2 = fmaf(qd, wr[t + 512], a2);
        a3 = fmaf(qd, wr[t + 768], a3);
    }
    qkb[h * 1024 + t]       = f2bf(a0 * SCALE);
    qkb[h * 1024 + t + 256] = f2bf(a1 * SCALE);
    qkb[h * 1024 + t + 512] = f2bf(a2 * SCALE);
    qkb[h * 1024 + t + 768] = f2bf(a3 * SCALE);
    if (t < 64) {
        const float* bk = ipb + 1024 + h * 128;
        float p = qs[t] * bk[t] + qs[t + 64] * bk[t + 64];
        #pragma unroll
        for (int m = 32; m >= 1; m >>= 1) p += __shfl_xor(p, m);
        if (t == 0) sb[h] = p * SCALE;
    }
}

// ---------------------------------------------------------------------------
// Kernel 4: per-patch fused gather + scores + softmax + attention mix
// grid 2048 x 256.  Outputs M[h][bp][j] (bf16) and pv[bp] (f32 0/1).
__global__ __launch_bounds__(256) void k_attn(
    const int* __restrict__ tok_ids, const int* __restrict__ amask,
    const float* __restrict__ emb, const unsigned short* __restrict__ qkb,
    const float* __restrict__ sb, unsigned short* __restrict__ Mout,
    float* __restrict__ pv) {
    // tok rows padded +16 bf16 (row stride 1040 elems = 2080 B) for bank spread
    __shared__ unsigned short tokL[16][1040];   // 33280 B
    __shared__ unsigned short qkL[8][1024];     // 16384 B
    __shared__ float scoresL[16][8];
    __shared__ float attnL[16][8];
    __shared__ float safeL[16];
    __shared__ int   tokid[16];

    int bp = blockIdx.x, t = threadIdx.x;

    if (t < 16) {
        tokid[t] = tok_ids[bp * 16 + t];
        safeL[t] = amask[bp * 16 + t] ? 1.f : 0.f;
    }
    __syncthreads();
    if (t == 0) {
        int any = 0;
        for (int l = 0; l < 16; ++l) any |= (safeL[l] > 0.f);
        pv[bp] = any ? 1.f : 0.f;
        if (!any) safeL[0] = 1.f;   // safe softmax: force pos 0 valid
    }
    // stage qk (bf16, no pad) into LDS: 1024 uint4 total
    {
        const uint4* src = (const uint4*)qkb;
        uint4* dst = (uint4*)&qkL[0][0];
        #pragma unroll
        for (int i = 0; i < 4; ++i) dst[t + i * 256] = src[t + i * 256];
    }
    // gather 16 embedding rows -> LDS bf16 (coalesced 256B segments per row)
    {
        int row = t >> 4, c = t & 15;
        const float* erow = emb + (size_t)tokid[row] * 1024;
        #pragma unroll
        for (int i = 0; i < 16; ++i) {
            int j4 = c + i * 16;
            float4 f = *(const float4*)(erow + j4 * 4);
            ushort4 o; o.x = f2bf(f.x); o.y = f2bf(f.y); o.z = f2bf(f.z); o.w = f2bf(f.w);
            *(ushort4*)(&tokL[row][j4 * 4]) = o;
        }
    }
    __syncthreads();

    // scores: thread (l = t>>4, seg = t&15) accumulates partial dot over
    // j in [seg*64, seg*64+64) for all 8 heads; seg-rotated read order.
    int l = t >> 4, seg = t & 15;
    float acc[8];
    #pragma unroll
    for (int h = 0; h < 8; ++h) acc[h] = 0.f;
    {
        const uint4* tokrow = (const uint4*)&tokL[l][0];
        #pragma unroll
        for (int ii = 0; ii < 8; ++ii) {
            int iofs = (seg + ii) & 7;
            uint4 tv = tokrow[seg * 8 + iofs];
            float t0 = bflo(tv.x), t1 = bfhi(tv.x), t2 = bflo(tv.y), t3 = bfhi(tv.y);
            float t4 = bflo(tv.z), t5 = bfhi(tv.z), t6 = bflo(tv.w), t7 = bfhi(tv.w);
            #pragma unroll
            for (int h = 0; h < 8; ++h) {
                uint4 qv = *(const uint4*)(&qkL[h][seg * 64 + iofs * 8]);
                float s = acc[h];
                s = fmaf(t0, bflo(qv.x), s); s = fmaf(t1, bfhi(qv.x), s);
                s = fmaf(t2, bflo(qv.y), s); s = fmaf(t3, bfhi(qv.y), s);
                s = fmaf(t4, bflo(qv.z), s); s = fmaf(t5, bfhi(qv.z), s);
                s = fmaf(t6, bflo(qv.w), s); s = fmaf(t7, bfhi(qv.w), s);
                acc[h] = s;
            }
        }
    }
    // reduce over seg (16-lane groups share l)
    #pragma unroll
    for (int h = 0; h < 8; ++h) {
        float a = acc[h];
        a += __shfl_xor(a, 1); a += __shfl_xor(a, 2);
        a += __shfl_xor(a, 4); a += __shfl_xor(a, 8);
        acc[h] = a;
    }
    if (seg < 8) {
        float v = acc[0];
        #pragma unroll
        for (int h = 1; h < 8; ++h) v = (seg == h) ? acc[h] : v;
        scoresL[l][seg] = v;
    }
    __syncthreads();

    // masked softmax over l per head (16-lane groups)
    if (t < 128) {
        int hh = t >> 4, ll = t & 15;
        float s = (safeL[ll] > 0.f) ? (scoresL[ll][hh] + sb[hh]) : -1e30f;
        float mx = s;
        mx = fmaxf(mx, __shfl_xor(mx, 1)); mx = fmaxf(mx, __shfl_xor(mx, 2));
        mx = fmaxf(mx, __shfl_xor(mx, 4)); mx = fmaxf(mx, __shfl_xor(mx, 8));
        float e = __expf(s - mx);
        float sum = e;
        sum += __shfl_xor(sum, 1); sum += __shfl_xor(sum, 2);
        sum += __shfl_xor(sum, 4); sum += __shfl_xor(sum, 8);
        attnL[ll][hh] = e / sum;
    }
    __syncthreads();

    // mix: m[h][j] = sum_l attn[h][l] * tok[l][j]; thread owns 4 j's
    float macc[8][4];
    #pragma unroll
    for (int h = 0; h < 8; ++h)
        #pragma unroll
        for (int c = 0; c < 4; ++c) macc[h][c] = 0.f;
    #pragma unroll
    for (int ll = 0; ll < 16; ++ll) {
        uint2 tv = *(const uint2*)(&tokL[ll][t * 4]);
        float t0 = bflo(tv.x), t1 = bfhi(tv.x), t2 = bflo(tv.y), t3 = bfhi(tv.y);
        float4 a0 = *(const float4*)(&attnL[ll][0]);
        float4 a1 = *(const float4*)(&attnL[ll][4]);
        macc[0][0] = fmaf(a0.x, t0, macc[0][0]); macc[0][1] = fmaf(a0.x, t1, macc[0][1]);
        macc[0][2] = fmaf(a0.x, t2, macc[0][2]); macc[0][3] = fmaf(a0.x, t3, macc[0][3]);
        macc[1][0] = fmaf(a0.y, t0, macc[1][0]); macc[1][1] = fmaf(a0.y, t1, macc[1][1]);
        macc[1][2] = fmaf(a0.y, t2, macc[1][2]); macc[1][3] = fmaf(a0.y, t3, macc[1][3]);
        macc[2][0] = fmaf(a0.z, t0, macc[2][0]); macc[2][1] = fmaf(a0.z, t1, macc[2][1]);
        macc[2][2] = fmaf(a0.z, t2, macc[2][2]); macc[2][3] = fmaf(a0.z, t3, macc[2][3]);
        macc[3][0] = fmaf(a0.w, t0, macc[3][0]); macc[3][1] = fmaf(a0.w, t1, macc[3][1]);
        macc[3][2] = fmaf(a0.w, t2, macc[3][2]); macc[3][3] = fmaf(a0.w, t3, macc[3][3]);
        macc[4][0] = fmaf(a1.x, t0, macc[4][0]); macc[4][1] = fmaf(a1.x, t1, macc[4][1]);
        macc[4][2] = fmaf(a1.x, t2, macc[4][2]); macc[4][3] = fmaf(a1.x, t3, macc[4][3]);
        macc[5][0] = fmaf(a1.y, t0, macc[5][0]); macc[5][1] = fmaf(a1.y, t1, macc[5][1]);
        macc[5][2] = fmaf(a1.y, t2, macc[5][2]); macc[5][3] = fmaf(a1.y, t3, macc[5][3]);
        macc[6][0] = fmaf(a1.z, t0, macc[6][0]); macc[6][1] = fmaf(a1.z, t1, macc[6][1]);
        macc[6][2] = fmaf(a1.z, t2, macc[6][2]); macc[6][3] = fmaf(a1.z, t3, macc[6][3]);
        macc[7][0] = fmaf(a1.w, t0, macc[7][0]); macc[7][1] = fmaf(a1.w, t1, macc[7][1]);
        macc[7][2] = fmaf(a1.w, t2, macc[7][2]); macc[7][3] = fmaf(a1.w, t3, macc[7][3]);
    }
    #pragma unroll
    for (int h = 0; h < 8; ++h) {
        ushort4 o;
        o.x = f2bf(macc[h][0]); o.y = f2bf(macc[h][1]);
        o.z = f2bf(macc[h][2]); o.w = f2bf(macc[h][3]);
        *(ushort4*)(Mout + ((size_t)(h * 2048 + bp)) * 1024 + t * 4) = o;
    }
}

// ---------------------------------------------------------------------------
// Shared 64x64x1024 NT bf16 MFMA mainloop (BK=32).  A [.,1024] rows m0..m0+63,
// Bm pre-offset to its n-rows.  LDS rows padded to 40 elems (80 B stride).
__device__ inline void gemm_tile_64x64(
    const unsigned short* __restrict__ A, const unsigned short* __restrict__ Bm,
    int m0, f32x4v acc[4], unsigned short* As, unsigned short* Bs) {
    int t = threadIdx.x;
    int row = t >> 2, seg = t & 3;
    int wave = t >> 6, lane = t & 63, lrow = lane & 15, quad = lane >> 4;
    #pragma unroll
    for (int nt = 0; nt < 4; ++nt) acc[nt] = (f32x4v){0.f, 0.f, 0.f, 0.f};
    for (int step = 0; step < 32; ++step) {
        int k0 = step * 32;
        uint4 av = *(const uint4*)(A  + (size_t)(m0 + row) * 1024 + k0 + seg * 8);
        uint4 bv = *(const uint4*)(Bm + (size_t)row * 1024 + k0 + seg * 8);
        __syncthreads();
        *(uint4*)(As + row * 40 + seg * 8) = av;
        *(uint4*)(Bs + row * 40 + seg * 8) = bv;
        __syncthreads();
        s16x8 af = *(const s16x8*)(As + (wave * 16 + lrow) * 40 + quad * 8);
        #pragma unroll
        for (int nt = 0; nt < 4; ++nt) {
            s16x8 bf = *(const s16x8*)(Bs + (nt * 16 + lrow) * 40 + quad * 8);
            acc[nt] = __builtin_amdgcn_mfma_f32_16x16x32_bf16(af, bf, acc[nt], 0, 0, 0);
        }
    }
}

// Kernel 5: ctx[bp][h*128+n] = M_h[bp,:] . wv_h[n,:] + bv   grid (32,2,8)
__global__ __launch_bounds__(256) void k_gemm_ctx(
    const unsigned short* __restrict__ M, const unsigned short* __restrict__ wv,
    const float* __restrict__ ipb, unsigned short* __restrict__ ctx) {
    __shared__ unsigned short As[64 * 40], Bs[64 * 40];
    int mb = blockIdx.x, nb = blockIdx.y, h = blockIdx.z;
    int m0 = mb * 64, nloc0 = nb * 64;
    const unsigned short* A  = M + (size_t)h * 2048 * 1024;
    const unsigned short* Bm = wv + (size_t)(h * 128 + nloc0) * 1024;
    f32x4v acc[4];
    gemm_tile_64x64(A, Bm, m0, acc, As, Bs);
    int lane = threadIdx.x & 63, wave = threadIdx.x >> 6;
    int lrow = lane & 15, quad = lane >> 4;
    #pragma unroll
    for (int nt = 0; nt < 4; ++nt) {
        int n_g = h * 128 + nloc0 + nt * 16 + lrow;
        float bias = ipb[2048 + n_g];
        #pragma unroll
        for (int r = 0; r < 4; ++r) {
            int row_g = m0 + wave * 16 + quad * 4 + r;
            ctx[(size_t)row_g * 1024 + n_g] = f2bf(acc[nt][r] + bias);
        }
    }
}

// Kernel 6: out[bp][n] = (ctx[bp,:] . out_w[n,:] + out_b[n]) * pv[bp]
// grid (32,16); nb==0 blocks also write the pv tail.
__global__ __launch_bounds__(256) void k_gemm_out(
    const unsigned short* __restrict__ ctx, const unsigned short* __restrict__ ow,
    const float* __restrict__ outb, const float* __restrict__ pv,
    float* __restrict__ out) {
    __shared__ unsigned short As[64 * 40], Bs[64 * 40];
    int mb = blockIdx.x, nb = blockIdx.y;
    int m0 = mb * 64, n0 = nb * 64;
    f32x4v acc[4];
    gemm_tile_64x64(ctx, ow + (size_t)n0 * 1024, m0, acc, As, Bs);
    int t = threadIdx.x;
    int lane = t & 63, wave = t >> 6, lrow = lane & 15, quad = lane >> 4;
    #pragma unroll
    for (int nt = 0; nt < 4; ++nt) {
        int n_g = n0 + nt * 16 + lrow;
        float bias = outb[n_g];
        #pragma unroll
        for (int r = 0; r < 4; ++r) {
            int row_g = m0 + wave * 16 + quad * 4 + r;
            out[(size_t)row_g * 1024 + n_g] = (acc[nt][r] + bias) * pv[row_g];
        }
    }
    if (nb == 0 && t < 64) out[OUT_LATENT + m0 + t] = pv[m0 + t];
}

// ---------------------------------------------------------------------------
extern "C" void kernel_launch(void* const* d_in, const int* in_sizes, int n_in,
                              void* d_out, int out_size, void* d_ws, size_t ws_size,
                              hipStream_t stream) {
    const int*   tok = (const int*)d_in[0];
    const int*   msk = (const int*)d_in[1];
    const float* emb = (const float*)d_in[2];
    const float* pq  = (const float*)d_in[3];
    const float* ipw = (const float*)d_in[4];
    const float* ipb = (const float*)d_in[5];
    const float* ow  = (const float*)d_in[6];
    const float* ob  = (const float*)d_in[7];
    float* out = (float*)d_out;
    char* ws = (char*)d_ws;

    // workspace layout (total ~40.1 MB)
    float*          q_f   = (float*)(ws + 0);                       // 4 KB
    float*          sb_f  = (float*)(ws + 4096);                    // 32 B
    float*          pv_f  = (float*)(ws + 8192);                    // 8 KB
    unsigned short* qk_b  = (unsigned short*)(ws + 16384);          // 16 KB
    unsigned short* wv_b  = (unsigned short*)(ws + 32768);          // 2 MB
    unsigned short* ow_b  = (unsigned short*)(ws + 32768 + 2097152);            // 2 MB
    unsigned short* ctx_b = (unsigned short*)(ws + 32768 + 2 * 2097152);        // 4 MB
    unsigned short* M_b   = (unsigned short*)(ws + 32768 + 2 * 2097152 + 4194304); // 32 MB

    k_convw<<<dim3(2048), dim3(256), 0, stream>>>(ipw + (size_t)2048 * 1024, ow, wv_b, ow_b);
    k_qvec <<<dim3(256),  dim3(256), 0, stream>>>(pq, ipw, ipb, q_f);
    k_qk   <<<dim3(8),    dim3(256), 0, stream>>>(q_f, ipw, ipb, qk_b, sb_f);
    k_attn <<<dim3(2048), dim3(256), 0, stream>>>(tok, msk, emb, qk_b, sb_f, M_b, pv_f);
    k_gemm_ctx<<<dim3(32, 2, 8), dim3(256), 0, stream>>>(M_b, wv_b, ipb, ctx_b);
    k_gemm_out<<<dim3(32, 16, 1), dim3(256), 0, stream>>>(ctx_b, ow_b, ob, pv_f, out);
}

// Round 2
// 267.313 us; speedup vs baseline: 1.0360x; 1.0360x over previous
//
#include <hip/hip_runtime.h>
#include <stdint.h>

#define OUT_LATENT (2048*1024)
#define SCALE 0.08838834764831845f  // 1/sqrt(128)

typedef float f32x4v __attribute__((ext_vector_type(4)));
typedef short s16x8  __attribute__((ext_vector_type(8)));

static __device__ inline unsigned short f2bf(float f) {
    union { float f; uint32_t u; } v; v.f = f;
    uint32_t u = v.u;
    return (unsigned short)((u + 0x7FFFu + ((u >> 16) & 1u)) >> 16); // RNE
}
static __device__ inline float bflo(uint32_t u) {
    union { uint32_t u; float f; } v; v.u = u << 16; return v.f;
}
static __device__ inline float bfhi(uint32_t u) {
    union { uint32_t u; float f; } v; v.u = u & 0xFFFF0000u; return v.f;
}

// async global->LDS, 16 B per lane (global_load_lds_dwordx4)
static __device__ __forceinline__ void async16(const unsigned short* g, unsigned short* l) {
    __builtin_amdgcn_global_load_lds(
        (const __attribute__((address_space(1))) void*)g,
        (__attribute__((address_space(3))) void*)l, 16, 0, 0);
}

// ---------------------------------------------------------------------------
// Kernel 1: convert wv (rows 2048..3071 of in_proj_w) and out_w to bf16
__global__ __launch_bounds__(256) void k_convw(
    const float* __restrict__ wv_src, const float* __restrict__ ow_src,
    unsigned short* __restrict__ wv_dst, unsigned short* __restrict__ ow_dst) {
    int t = threadIdx.x, b = blockIdx.x;
    const float* src; unsigned short* dst; int idx;
    if (b < 1024) { src = wv_src; dst = wv_dst; idx = b * 1024 + t * 4; }
    else          { src = ow_src; dst = ow_dst; idx = (b - 1024) * 1024 + t * 4; }
    float4 f = *(const float4*)(src + idx);
    ushort4 o; o.x = f2bf(f.x); o.y = f2bf(f.y); o.z = f2bf(f.z); o.w = f2bf(f.w);
    *(ushort4*)(dst + idx) = o;
}

// ---------------------------------------------------------------------------
// Kernel 2: q[d] = patch_query . wq[d,:] + bq[d].  grid 256 x 256 (1 wave/d)
__global__ __launch_bounds__(256) void k_qvec(
    const float* __restrict__ pq, const float* __restrict__ ipw,
    const float* __restrict__ ipb, float* __restrict__ qv) {
    int t = threadIdx.x, wave = t >> 6, lane = t & 63;
    int d = blockIdx.x * 4 + wave;
    const float* wrow = ipw + (size_t)d * 1024;
    float acc = 0.f;
    #pragma unroll
    for (int i = 0; i < 16; ++i) { int j = lane + i * 64; acc = fmaf(pq[j], wrow[j], acc); }
    #pragma unroll
    for (int m = 32; m >= 1; m >>= 1) acc += __shfl_xor(acc, m);
    if (lane == 0) qv[d] = acc + ipb[d];
}

// ---------------------------------------------------------------------------
// Kernel 3: qk[h][j] = SCALE * sum_d q[h*128+d] * wk[h*128+d][j]  (bf16)
//           sb[h]   = SCALE * q_h . bk_h
// grid (8 h, 8 jseg) x 256: jl = t&127 covers 128 j, dh = t>>7 splits d.
__global__ __launch_bounds__(256) void k_qk(
    const float* __restrict__ qv, const float* __restrict__ ipw,
    const float* __restrict__ ipb, unsigned short* __restrict__ qkb,
    float* __restrict__ sb) {
    __shared__ float qs[128];
    __shared__ float part[128];
    int h = blockIdx.x, jseg = blockIdx.y, t = threadIdx.x;
    int jl = t & 127, dh = t >> 7;
    if (t < 128) qs[t] = qv[h * 128 + t];
    __syncthreads();
    float acc = 0.f;
    const float* wbase = ipw + (size_t)(1024 + h * 128 + dh * 64) * 1024 + jseg * 128 + jl;
    #pragma unroll 8
    for (int d = 0; d < 64; ++d)
        acc = fmaf(qs[dh * 64 + d], wbase[(size_t)d * 1024], acc);
    if (dh) part[jl] = acc;
    __syncthreads();
    if (!dh) qkb[h * 1024 + jseg * 128 + jl] = f2bf((acc + part[jl]) * SCALE);
    if (jseg == 0 && t < 64) {
        const float* bk = ipb + 1024 + h * 128;
        float p = qs[t] * bk[t] + qs[t + 64] * bk[t + 64];
        #pragma unroll
        for (int m = 32; m >= 1; m >>= 1) p += __shfl_xor(p, m);
        if (t == 0) sb[h] = p * SCALE;
    }
}

// ---------------------------------------------------------------------------
// Kernel 4: per-patch fused gather + MFMA scores + softmax + attention mix.
// grid 2048 x 256.  Outputs M[h][bp][j] (bf16) and pv[bp] (f32 0/1).
__global__ __launch_bounds__(256) void k_attn(
    const int* __restrict__ tok_ids, const int* __restrict__ amask,
    const float* __restrict__ emb, const unsigned short* __restrict__ qkb,
    const float* __restrict__ sb, unsigned short* __restrict__ Mout,
    float* __restrict__ pv) {
    __shared__ unsigned short tokL[16][1032];   // +8 pad: row stride 2064 B
    __shared__ float scoresP[4][16][8];         // per-wave partial score tiles
    __shared__ float attnL[16][8];
    __shared__ int allzL;

    int bp = blockIdx.x, t = threadIdx.x;
    int wave = t >> 6, lane = t & 63, lrow = lane & 15, quad = lane >> 4;

    // B-frag prefetch for scores MFMA: wave w covers k in [w*256, w*256+256).
    // B[n=lane&15][k]: head = lane&7 (cols 8..15 duplicate cols 0..7, unused).
    s16x8 bfr[8];
    {
        const unsigned short* qbase = qkb + (lane & 7) * 1024 + wave * 256 + quad * 8;
        #pragma unroll
        for (int s = 0; s < 8; ++s) bfr[s] = *(const s16x8*)(qbase + s * 32);
    }

    // gather 16 embedding rows -> LDS bf16
    {
        int row = t >> 4, c = t & 15;
        int tid = tok_ids[bp * 16 + row];
        const float* erow = emb + (size_t)tid * 1024;
        #pragma unroll
        for (int i = 0; i < 16; ++i) {
            int j4 = c + i * 16;
            float4 f = *(const float4*)(erow + j4 * 4);
            ushort4 o; o.x = f2bf(f.x); o.y = f2bf(f.y); o.z = f2bf(f.z); o.w = f2bf(f.w);
            *(ushort4*)(&tokL[row][j4 * 4]) = o;
        }
    }
    // patch-valid flag
    if (t < 16) {
        int any = (amask[bp * 16 + t] != 0);
        any |= __shfl_xor(any, 1); any |= __shfl_xor(any, 2);
        any |= __shfl_xor(any, 4); any |= __shfl_xor(any, 8);
        if (t == 0) { pv[bp] = any ? 1.f : 0.f; allzL = any ? 0 : 1; }
    }
    __syncthreads();

    // scores via MFMA: D[l][h] partial over this wave's k-range
    {
        f32x4v acc = (f32x4v){0.f, 0.f, 0.f, 0.f};
        const unsigned short* arow = &tokL[lrow][wave * 256 + quad * 8];
        #pragma unroll
        for (int s = 0; s < 8; ++s) {
            s16x8 af = *(const s16x8*)(arow + s * 32);
            acc = __builtin_amdgcn_mfma_f32_16x16x32_bf16(af, bfr[s], acc, 0, 0, 0);
        }
        if (lrow < 8) {
            #pragma unroll
            for (int r = 0; r < 4; ++r) scoresP[wave][quad * 4 + r][lrow] = acc[r];
        }
    }
    __syncthreads();

    // masked softmax over l per head (16-lane groups; t<128: hh=t>>4, ll=t&15)
    if (t < 128) {
        int hh = t >> 4, ll = t & 15;
        float s = scoresP[0][ll][hh] + scoresP[1][ll][hh]
                + scoresP[2][ll][hh] + scoresP[3][ll][hh] + sb[hh];
        bool valid = (amask[bp * 16 + ll] != 0) || (allzL && ll == 0);
        s = valid ? s : -1e30f;
        float mx = s;
        mx = fmaxf(mx, __shfl_xor(mx, 1)); mx = fmaxf(mx, __shfl_xor(mx, 2));
        mx = fmaxf(mx, __shfl_xor(mx, 4)); mx = fmaxf(mx, __shfl_xor(mx, 8));
        float e = __expf(s - mx);
        float sum = e;
        sum += __shfl_xor(sum, 1); sum += __shfl_xor(sum, 2);
        sum += __shfl_xor(sum, 4); sum += __shfl_xor(sum, 8);
        attnL[ll][hh] = e / sum;
    }
    __syncthreads();

    // mix: m[h][j] = sum_l attn[h][l] * tok[l][j]; thread owns 4 j's
    float macc[8][4];
    #pragma unroll
    for (int h = 0; h < 8; ++h)
        #pragma unroll
        for (int c = 0; c < 4; ++c) macc[h][c] = 0.f;
    #pragma unroll
    for (int ll = 0; ll < 16; ++ll) {
        uint2 tv = *(const uint2*)(&tokL[ll][t * 4]);
        float t0 = bflo(tv.x), t1 = bfhi(tv.x), t2 = bflo(tv.y), t3 = bfhi(tv.y);
        float4 a0 = *(const float4*)(&attnL[ll][0]);
        float4 a1 = *(const float4*)(&attnL[ll][4]);
        macc[0][0] = fmaf(a0.x, t0, macc[0][0]); macc[0][1] = fmaf(a0.x, t1, macc[0][1]);
        macc[0][2] = fmaf(a0.x, t2, macc[0][2]); macc[0][3] = fmaf(a0.x, t3, macc[0][3]);
        macc[1][0] = fmaf(a0.y, t0, macc[1][0]); macc[1][1] = fmaf(a0.y, t1, macc[1][1]);
        macc[1][2] = fmaf(a0.y, t2, macc[1][2]); macc[1][3] = fmaf(a0.y, t3, macc[1][3]);
        macc[2][0] = fmaf(a0.z, t0, macc[2][0]); macc[2][1] = fmaf(a0.z, t1, macc[2][1]);
        macc[2][2] = fmaf(a0.z, t2, macc[2][2]); macc[2][3] = fmaf(a0.z, t3, macc[2][3]);
        macc[3][0] = fmaf(a0.w, t0, macc[3][0]); macc[3][1] = fmaf(a0.w, t1, macc[3][1]);
        macc[3][2] = fmaf(a0.w, t2, macc[3][2]); macc[3][3] = fmaf(a0.w, t3, macc[3][3]);
        macc[4][0] = fmaf(a1.x, t0, macc[4][0]); macc[4][1] = fmaf(a1.x, t1, macc[4][1]);
        macc[4][2] = fmaf(a1.x, t2, macc[4][2]); macc[4][3] = fmaf(a1.x, t3, macc[4][3]);
        macc[5][0] = fmaf(a1.y, t0, macc[5][0]); macc[5][1] = fmaf(a1.y, t1, macc[5][1]);
        macc[5][2] = fmaf(a1.y, t2, macc[5][2]); macc[5][3] = fmaf(a1.y, t3, macc[5][3]);
        macc[6][0] = fmaf(a1.z, t0, macc[6][0]); macc[6][1] = fmaf(a1.z, t1, macc[6][1]);
        macc[6][2] = fmaf(a1.z, t2, macc[6][2]); macc[6][3] = fmaf(a1.z, t3, macc[6][3]);
        macc[7][0] = fmaf(a1.w, t0, macc[7][0]); macc[7][1] = fmaf(a1.w, t1, macc[7][1]);
        macc[7][2] = fmaf(a1.w, t2, macc[7][2]); macc[7][3] = fmaf(a1.w, t3, macc[7][3]);
    }
    #pragma unroll
    for (int h = 0; h < 8; ++h) {
        ushort4 o;
        o.x = f2bf(macc[h][0]); o.y = f2bf(macc[h][1]);
        o.z = f2bf(macc[h][2]); o.w = f2bf(macc[h][3]);
        *(ushort4*)(Mout + ((size_t)(h * 2048 + bp)) * 1024 + t * 4) = o;
    }
}

// ---------------------------------------------------------------------------
// m97-style 128x128x1024 NT bf16 MFMA mainloop, BK=32, global_load_lds x16.
// A, B pre-offset to their 128-row ranges, both row-major stride 1024.
__device__ __forceinline__ void gemm128_mainloop(
    const unsigned short* __restrict__ A, const unsigned short* __restrict__ B,
    unsigned short* As, unsigned short* Bs, f32x4v acc[4][4]) {
    int t = threadIdx.x;
    int wave = t >> 6, lane = t & 63, lrow = lane & 15, quad = lane >> 4;
    int wm = wave & 1, wn = wave >> 1;
    int srow = t >> 2, sseg = (t & 3) * 8;
    #pragma unroll
    for (int mi = 0; mi < 4; ++mi)
        #pragma unroll
        for (int ni = 0; ni < 4; ++ni) acc[mi][ni] = (f32x4v){0.f, 0.f, 0.f, 0.f};
    for (int step = 0; step < 32; ++step) {
        int k0 = step * 32;
        __syncthreads();
        async16(A + (size_t)srow * 1024 + k0 + sseg,        As + t * 8);
        async16(A + (size_t)(srow + 64) * 1024 + k0 + sseg, As + (256 + t) * 8);
        async16(B + (size_t)srow * 1024 + k0 + sseg,        Bs + t * 8);
        async16(B + (size_t)(srow + 64) * 1024 + k0 + sseg, Bs + (256 + t) * 8);
        __syncthreads();
        s16x8 af[4], bf[4];
        #pragma unroll
        for (int i = 0; i < 4; ++i) {
            af[i] = *(const s16x8*)(As + (wm * 64 + i * 16 + lrow) * 32 + quad * 8);
            bf[i] = *(const s16x8*)(Bs + (wn * 64 + i * 16 + lrow) * 32 + quad * 8);
        }
        #pragma unroll
        for (int mi = 0; mi < 4; ++mi)
            #pragma unroll
            for (int ni = 0; ni < 4; ++ni)
                acc[mi][ni] = __builtin_amdgcn_mfma_f32_16x16x32_bf16(af[mi], bf[ni], acc[mi][ni], 0, 0, 0);
    }
}

// Kernel 5: ctx[bp][h*128+n] = M_h[bp,:] . wv_h[n,:] + bv   grid (16 mb, 8 h)
__global__ __launch_bounds__(256) void k_gemm_ctx(
    const unsigned short* __restrict__ M, const unsigned short* __restrict__ wv,
    const float* __restrict__ ipb, unsigned short* __restrict__ ctx) {
    __shared__ unsigned short As[128 * 32], Bs[128 * 32];
    int mb = blockIdx.x, h = blockIdx.y;
    f32x4v acc[4][4];
    gemm128_mainloop(M + ((size_t)h * 2048 + mb * 128) * 1024,
                     wv + (size_t)h * 128 * 1024, As, Bs, acc);
    int t = threadIdx.x, wave = t >> 6, lane = t & 63, lrow = lane & 15, quad = lane >> 4;
    int wm = wave & 1, wn = wave >> 1;
    #pragma unroll
    for (int ni = 0; ni < 4; ++ni) {
        int n_g = h * 128 + wn * 64 + ni * 16 + lrow;
        float bias = ipb[2048 + n_g];
        #pragma unroll
        for (int mi = 0; mi < 4; ++mi) {
            #pragma unroll
            for (int r = 0; r < 4; ++r) {
                int m_g = mb * 128 + wm * 64 + mi * 16 + quad * 4 + r;
                ctx[(size_t)m_g * 1024 + n_g] = f2bf(acc[mi][ni][r] + bias);
            }
        }
    }
}

// Kernel 6: out[bp][n] = (ctx[bp,:] . out_w[n,:] + out_b[n]) * pv[bp]
// grid (16 mb, 8 nb); nb==0 blocks write the pv tail.
__global__ __launch_bounds__(256) void k_gemm_out(
    const unsigned short* __restrict__ ctx, const unsigned short* __restrict__ ow,
    const float* __restrict__ outb, const float* __restrict__ pv,
    float* __restrict__ out) {
    __shared__ unsigned short As[128 * 32], Bs[128 * 32];
    int mb = blockIdx.x, nb = blockIdx.y;
    f32x4v acc[4][4];
    gemm128_mainloop(ctx + (size_t)mb * 128 * 1024,
                     ow + (size_t)nb * 128 * 1024, As, Bs, acc);
    int t = threadIdx.x, wave = t >> 6, lane = t & 63, lrow = lane & 15, quad = lane >> 4;
    int wm = wave & 1, wn = wave >> 1;
    #pragma unroll
    for (int ni = 0; ni < 4; ++ni) {
        int n_g = nb * 128 + wn * 64 + ni * 16 + lrow;
        float bias = outb[n_g];
        #pragma unroll
        for (int mi = 0; mi < 4; ++mi) {
            #pragma unroll
            for (int r = 0; r < 4; ++r) {
                int m_g = mb * 128 + wm * 64 + mi * 16 + quad * 4 + r;
                out[(size_t)m_g * 1024 + n_g] = (acc[mi][ni][r] + bias) * pv[m_g];
            }
        }
    }
    if (nb == 0 && t < 128) out[OUT_LATENT + mb * 128 + t] = pv[mb * 128 + t];
}

// ---------------------------------------------------------------------------
extern "C" void kernel_launch(void* const* d_in, const int* in_sizes, int n_in,
                              void* d_out, int out_size, void* d_ws, size_t ws_size,
                              hipStream_t stream) {
    const int*   tok = (const int*)d_in[0];
    const int*   msk = (const int*)d_in[1];
    const float* emb = (const float*)d_in[2];
    const float* pq  = (const float*)d_in[3];
    const float* ipw = (const float*)d_in[4];
    const float* ipb = (const float*)d_in[5];
    const float* ow  = (const float*)d_in[6];
    const float* ob  = (const float*)d_in[7];
    float* out = (float*)d_out;
    char* ws = (char*)d_ws;

    float*          q_f   = (float*)(ws + 0);                       // 4 KB
    float*          sb_f  = (float*)(ws + 4096);                    // 32 B
    float*          pv_f  = (float*)(ws + 8192);                    // 8 KB
    unsigned short* qk_b  = (unsigned short*)(ws + 16384);          // 16 KB
    unsigned short* wv_b  = (unsigned short*)(ws + 32768);          // 2 MB
    unsigned short* ow_b  = (unsigned short*)(ws + 32768 + 2097152);            // 2 MB
    unsigned short* ctx_b = (unsigned short*)(ws + 32768 + 2 * 2097152);        // 4 MB
    unsigned short* M_b   = (unsigned short*)(ws + 32768 + 2 * 2097152 + 4194304); // 32 MB

    k_convw<<<dim3(2048), dim3(256), 0, stream>>>(ipw + (size_t)2048 * 1024, ow, wv_b, ow_b);
    k_qvec <<<dim3(256),  dim3(256), 0, stream>>>(pq, ipw, ipb, q_f);
    k_qk   <<<dim3(8, 8), dim3(256), 0, stream>>>(q_f, ipw, ipb, qk_b, sb_f);
    k_attn <<<dim3(2048), dim3(256), 0, stream>>>(tok, msk, emb, qk_b, sb_f, M_b, pv_f);
    k_gemm_ctx<<<dim3(16, 8), dim3(256), 0, stream>>>(M_b, wv_b, ipb, ctx_b);
    k_gemm_out<<<dim3(16, 8), dim3(256), 0, stream>>>(ctx_b, ow_b, ob, pv_f, out);
}